// Round 2
// baseline (274.378 us; speedup 1.0000x reference)
//
#include <hip/hip_runtime.h>
#include <math.h>

#define IM 128
#define BZ 32

typedef float v4f __attribute__((ext_vector_type(4)));

// One block per (b, h) row of x = input[:,0,:,:].
//   t[v] = sum_w x[w] * exp(-2*pi*i*v*w/128)            (the ifft(fft2) collapse)
//   sep[b,v,h,w] = (Re t[v]*cos(2pi v w/128) - Im t[v]*sin(2pi v w/128)) / 128
// out layout: (B, 129, 128, 128); channel 128 = input[:,1,:,:].
__global__ __launch_bounds__(256) void kspace_kernel(const float* __restrict__ in,
                                                     float* __restrict__ out) {
    const int row = blockIdx.x;        // 0 .. BZ*IM-1
    const int b   = row >> 7;
    const int h   = row & (IM - 1);
    const int tid = threadIdx.x;       // 0 .. 255

    __shared__ float xr[IM];
    __shared__ float cs[IM];
    __shared__ float sn[IM];
    __shared__ float tre[IM];
    __shared__ float tim[IM];

    // ---- stage x row + twiddle table ----
    const float* xrow = in + (((size_t)b * 2 + 0) * IM + h) * IM;
    if (tid < IM) {
        xr[tid] = xrow[tid];
        float s, c;
        sincosf((float)(2.0 * M_PI / IM) * (float)tid, &s, &c);
        cs[tid] = c;
        sn[tid] = s;
    }
    __syncthreads();

    // ---- 128-point DFT: v = tid/2, each half sums 64 terms ----
    {
        const int v    = tid >> 1;
        const int part = tid & 1;
        float sre = 0.0f, sim = 0.0f;
        const int wbase = part * 64;
        #pragma unroll 8
        for (int i = 0; i < 64; ++i) {
            const int w = wbase + i;
            const int k = (v * w) & (IM - 1);
            const float xv = xr[w];
            sre += xv * cs[k];
            sim -= xv * sn[k];
        }
        // partner lanes are adjacent within the same 64-lane wave
        sre += __shfl_xor(sre, 1);
        sim += __shfl_xor(sim, 1);
        if (part == 0) {
            tre[v] = sre * (1.0f / IM);   // fold the /W scale in here
            tim[v] = sim * (1.0f / IM);
        }
    }
    __syncthreads();

    // ---- emit sep: 16 iterations x (8 v-rows x 128 w) via float4 NT stores ----
    float* outb = out + (size_t)b * 129 * IM * IM + (size_t)h * IM;
    const int vsub = tid >> 5;            // 0..7
    const int w0   = (tid & 31) * 4;      // 0,4,...,124
    #pragma unroll
    for (int it = 0; it < 16; ++it) {
        const int v = it * 8 + vsub;
        const float re = tre[v];
        const float im = tim[v];
        int k0 = (v * w0) & (IM - 1);
        int k1 = (k0 + v) & (IM - 1);
        int k2 = (k1 + v) & (IM - 1);
        int k3 = (k2 + v) & (IM - 1);
        v4f r;
        r.x = re * cs[k0] - im * sn[k0];
        r.y = re * cs[k1] - im * sn[k1];
        r.z = re * cs[k2] - im * sn[k2];
        r.w = re * cs[k3] - im * sn[k3];
        __builtin_nontemporal_store(r, (v4f*)(outb + (size_t)v * IM * IM + w0));
    }

    // ---- passthrough: out[b, 128, h, :] = input[b, 1, h, :] ----
    if (tid < 32) {
        const v4f* src = (const v4f*)(in + (((size_t)b * 2 + 1) * IM + h) * IM);
        v4f*       dst = (v4f*)(out + (((size_t)b * 129 + 128) * IM + h) * IM);
        __builtin_nontemporal_store(src[tid], dst + tid);
    }
}

extern "C" void kernel_launch(void* const* d_in, const int* in_sizes, int n_in,
                              void* d_out, int out_size, void* d_ws, size_t ws_size,
                              hipStream_t stream) {
    const float* in = (const float*)d_in[0];   // (32, 2, 128, 128) fp32; mask (d_in[1]) is unused
    float* out = (float*)d_out;                // (32, 129, 128, 128) fp32
    kspace_kernel<<<dim3(BZ * IM), dim3(256), 0, stream>>>(in, out);
}

// Round 3
// 274.210 us; speedup vs baseline: 1.0006x; 1.0006x over previous
//
#include <hip/hip_runtime.h>
#include <math.h>

#define IM 128
#define BZ 32

typedef float v4f __attribute__((ext_vector_type(4)));

// One block per (b, h) row of x = input[:,0,:,:].
//   t[v]        = sum_w x[w] * e^{-2pi i v w/128}        (ifft(fft2(x)) collapses to row DFT)
//   sep[b,v,h,w] = Re( t[v] * e^{+2pi i v w/128} ) / 128
// out layout: (B, 129, 128, 128); channel 128 = input[:,1,:,:].
// All twiddles via in-register phasor recurrences — zero LDS gathers (R2 was
// LDS-gather bound: banks {0,4,..,28} only -> >=4-way conflicts).
__global__ __launch_bounds__(256) void kspace_kernel(const float* __restrict__ in,
                                                     float* __restrict__ out) {
    const int row = blockIdx.x;        // 0 .. BZ*IM-1
    const int b   = row >> 7;
    const int h   = row & (IM - 1);
    const int tid = threadIdx.x;       // 0 .. 255

    const float A = 6.28318530717958647692f / (float)IM;   // 2*pi/128

    __shared__ float xr[IM];
    __shared__ float tre[IM];
    __shared__ float tim[IM];

    // ---- stage x row ----
    const float* xrow = in + (((size_t)b * 2 + 0) * IM + h) * IM;
    if (tid < IM) xr[tid] = xrow[tid];
    __syncthreads();

    // ---- 128-point DFT: v = tid/2, each half sums 64 terms, phasor recurrence ----
    {
        const int v     = tid >> 1;
        const int part  = tid & 1;
        const int wbase = part << 6;                       // 0 or 64

        // phasor p = e^{-2pi i v (wbase+i)/128}, step r = e^{-2pi i v/128}
        float pc, ps;
        { int k = (v * wbase) & (IM - 1); sincosf(A * (float)k, &ps, &pc); ps = -ps; }
        float rc, rs;
        sincosf(A * (float)v, &rs, &rc); rs = -rs;

        float sre = 0.0f, sim = 0.0f;
        #pragma unroll 8
        for (int i = 0; i < 64; ++i) {
            const float xv = xr[wbase + i];                // uniform-ish (2 addrs/wave): free
            sre = fmaf(xv, pc, sre);
            sim = fmaf(xv, ps, sim);
            const float npc = pc * rc - ps * rs;
            ps = fmaf(ps, rc, pc * rs);
            pc = npc;
        }
        sre += __shfl_xor(sre, 1);
        sim += __shfl_xor(sim, 1);
        if (part == 0) {
            tre[v] = sre * (1.0f / IM);
            tim[v] = sim * (1.0f / IM);
        }
    }
    __syncthreads();

    // ---- emit: thread (vsub = tid>>5, w0 = (tid&31)*4), 16 iters over v = it*8+vsub ----
    float* outb = out + (size_t)b * 129 * IM * IM + (size_t)h * IM;
    const int vsub = tid >> 5;            // 0..7
    const int w0   = (tid & 31) * 4;      // 0,4,...,124

    // P = e^{2pi i v w0/128} (v starts at vsub), per-iter P *= W, W = e^{2pi i 8 w0/128}
    // R = e^{2pi i v/128},                      per-iter R *= S, S = e^{i pi/8}
    float pc, ps;
    { int k = (vsub * w0) & (IM - 1); sincosf(A * (float)k, &ps, &pc); }
    float rc, rs;
    sincosf(A * (float)vsub, &rs, &rc);
    float wc, ws;
    { int k = (8 * w0) & (IM - 1); sincosf(A * (float)k, &ws, &wc); }
    const float sc = 0.92387953251128675613f;   // cos(pi/8)
    const float ss = 0.38268343236508977173f;   // sin(pi/8)

    #pragma unroll
    for (int it = 0; it < 16; ++it) {
        const int v = it * 8 + vsub;
        const float re = tre[v];          // 2 addresses per wave: conflict-free
        const float im = tim[v];

        v4f r;
        float c = pc, s = ps;
        r.x = re * c - im * s;
        float nc = c * rc - s * rs; s = fmaf(s, rc, c * rs); c = nc;
        r.y = re * c - im * s;
        nc = c * rc - s * rs; s = fmaf(s, rc, c * rs); c = nc;
        r.z = re * c - im * s;
        nc = c * rc - s * rs; s = fmaf(s, rc, c * rs); c = nc;
        r.w = re * c - im * s;
        __builtin_nontemporal_store(r, (v4f*)(outb + (size_t)v * IM * IM + w0));

        // advance recurrences for next v = v + 8
        nc = pc * wc - ps * ws; ps = fmaf(ps, wc, pc * ws); pc = nc;
        nc = rc * sc - rs * ss; rs = fmaf(rs, sc, rc * ss); rc = nc;
    }

    // ---- passthrough: out[b, 128, h, :] = input[b, 1, h, :] ----
    if (tid < 32) {
        const v4f* src = (const v4f*)(in + (((size_t)b * 2 + 1) * IM + h) * IM);
        v4f*       dst = (v4f*)(out + (((size_t)b * 129 + 128) * IM + h) * IM);
        __builtin_nontemporal_store(src[tid], dst + tid);
    }
}

extern "C" void kernel_launch(void* const* d_in, const int* in_sizes, int n_in,
                              void* d_out, int out_size, void* d_ws, size_t ws_size,
                              hipStream_t stream) {
    const float* in = (const float*)d_in[0];   // (32, 2, 128, 128) fp32; mask unused
    float* out = (float*)d_out;                // (32, 129, 128, 128) fp32
    kspace_kernel<<<dim3(BZ * IM), dim3(256), 0, stream>>>(in, out);
}

// Round 4
// 265.586 us; speedup vs baseline: 1.0331x; 1.0325x over previous
//
#include <hip/hip_runtime.h>
#include <math.h>

#define IM 128
#define BZ 32

typedef float v4f __attribute__((ext_vector_type(4)));

// One block per (b, h) row of x = input[:,0,:,:].
//   t[v]         = sum_w x[w] * e^{-2pi i v w/128}       (ifft(fft2(x)) collapses to row DFT)
//   sep[b,v,h,w] = Re( t[v] * e^{+2pi i v w/128} ) / 128
// out layout: (B, 129, 128, 128); channel 128 = input[:,1,:,:].
// Twiddles via in-register phasor recurrences (no LDS gathers).
// R4 experiment: plain stores instead of nontemporal — isolating NT-store
// drain rate vs the 6.36 TB/s the harness fill demonstrates with plain stores.
__global__ __launch_bounds__(256) void kspace_kernel(const float* __restrict__ in,
                                                     float* __restrict__ out) {
    const int row = blockIdx.x;        // 0 .. BZ*IM-1
    const int b   = row >> 7;
    const int h   = row & (IM - 1);
    const int tid = threadIdx.x;       // 0 .. 255

    const float A = 6.28318530717958647692f / (float)IM;   // 2*pi/128

    __shared__ float xr[IM];
    __shared__ float tre[IM];
    __shared__ float tim[IM];

    // ---- stage x row ----
    const float* xrow = in + (((size_t)b * 2 + 0) * IM + h) * IM;
    if (tid < IM) xr[tid] = xrow[tid];
    __syncthreads();

    // ---- 128-point DFT: v = tid/2, each half sums 64 terms, phasor recurrence ----
    {
        const int v     = tid >> 1;
        const int part  = tid & 1;
        const int wbase = part << 6;                       // 0 or 64

        // phasor p = e^{-2pi i v (wbase+i)/128}, step r = e^{-2pi i v/128}
        float pc, ps;
        { int k = (v * wbase) & (IM - 1); sincosf(A * (float)k, &ps, &pc); ps = -ps; }
        float rc, rs;
        sincosf(A * (float)v, &rs, &rc); rs = -rs;

        float sre = 0.0f, sim = 0.0f;
        #pragma unroll 8
        for (int i = 0; i < 64; ++i) {
            const float xv = xr[wbase + i];                // 2 addrs/wave: conflict-free
            sre = fmaf(xv, pc, sre);
            sim = fmaf(xv, ps, sim);
            const float npc = pc * rc - ps * rs;
            ps = fmaf(ps, rc, pc * rs);
            pc = npc;
        }
        sre += __shfl_xor(sre, 1);
        sim += __shfl_xor(sim, 1);
        if (part == 0) {
            tre[v] = sre * (1.0f / IM);
            tim[v] = sim * (1.0f / IM);
        }
    }
    __syncthreads();

    // ---- emit: thread (vsub = tid>>5, w0 = (tid&31)*4), 16 iters over v = it*8+vsub ----
    float* outb = out + (size_t)b * 129 * IM * IM + (size_t)h * IM;
    const int vsub = tid >> 5;            // 0..7
    const int w0   = (tid & 31) * 4;      // 0,4,...,124

    // P = e^{2pi i v w0/128} (v starts at vsub), per-iter P *= W, W = e^{2pi i 8 w0/128}
    // R = e^{2pi i v/128},                       per-iter R *= S, S = e^{i pi/8}
    float pc, ps;
    { int k = (vsub * w0) & (IM - 1); sincosf(A * (float)k, &ps, &pc); }
    float rc, rs;
    sincosf(A * (float)vsub, &rs, &rc);
    float wc, ws;
    { int k = (8 * w0) & (IM - 1); sincosf(A * (float)k, &ws, &wc); }
    const float sc = 0.92387953251128675613f;   // cos(pi/8)
    const float ss = 0.38268343236508977173f;   // sin(pi/8)

    #pragma unroll
    for (int it = 0; it < 16; ++it) {
        const int v = it * 8 + vsub;
        const float re = tre[v];          // 2 addresses per wave: conflict-free
        const float im = tim[v];

        v4f r;
        float c = pc, s = ps;
        r.x = re * c - im * s;
        float nc = c * rc - s * rs; s = fmaf(s, rc, c * rs); c = nc;
        r.y = re * c - im * s;
        nc = c * rc - s * rs; s = fmaf(s, rc, c * rs); c = nc;
        r.z = re * c - im * s;
        nc = c * rc - s * rs; s = fmaf(s, rc, c * rs); c = nc;
        r.w = re * c - im * s;
        *(v4f*)(outb + (size_t)v * IM * IM + w0) = r;

        // advance recurrences for next v = v + 8
        nc = pc * wc - ps * ws; ps = fmaf(ps, wc, pc * ws); pc = nc;
        nc = rc * sc - rs * ss; rs = fmaf(rs, sc, rc * ss); rc = nc;
    }

    // ---- passthrough: out[b, 128, h, :] = input[b, 1, h, :] ----
    if (tid < 32) {
        const v4f* src = (const v4f*)(in + (((size_t)b * 2 + 1) * IM + h) * IM);
        v4f*       dst = (v4f*)(out + (((size_t)b * 129 + 128) * IM + h) * IM);
        dst[tid] = src[tid];
    }
}

extern "C" void kernel_launch(void* const* d_in, const int* in_sizes, int n_in,
                              void* d_out, int out_size, void* d_ws, size_t ws_size,
                              hipStream_t stream) {
    const float* in = (const float*)d_in[0];   // (32, 2, 128, 128) fp32; mask unused
    float* out = (float*)d_out;                // (32, 129, 128, 128) fp32
    kspace_kernel<<<dim3(BZ * IM), dim3(256), 0, stream>>>(in, out);
}